// Round 1
// baseline (151.525 us; speedup 1.0000x reference)
//
#include <hip/hip_runtime.h>

// Problem constants (from reference)
#define NROW 513   // N+1
#define NCOL 65    // D+1
#define DD   64    // D
#define NN   512   // N (attention truncation + divisor)
#define NLAYER 4
#define TPB  1024  // 16 waves
#define NGRP 16    // TPB/64 wave-groups for the s-phase

// Math: per batch b, X = Z[:, :64] is invariant; y = Z[:,64].
// layer l: s = X[:512]^T y[:512];  r = r*gamma_l + (q_l/512) * X s;  y += r*alpha_l
// q_l = mean(diag(allparam[l,0,1]))

__launch_bounds__(TPB)
__global__ void tf_kernel(const float* __restrict__ Zin,
                          const float* __restrict__ allparam,
                          const float* __restrict__ gam,
                          const float* __restrict__ alp,
                          float* __restrict__ out) {
    // LDS: full tile, row stride 65 (odd -> (n*65+j)%32 = (n+j)%32, <=2 lanes/bank)
    __shared__ float Zs[NROW * NCOL];      // 133,380 B
    __shared__ float rS[NROW];             // residual column (general gamma/alpha)
    __shared__ float sred[NGRP][DD];       // partial s reductions
    __shared__ float sv[DD];               // s vector
    __shared__ float qs[NLAYER];

    const int tid = threadIdx.x;
    const int b = blockIdx.x;
    const long base = (long)b * (NROW * NCOL);

    // --- q_l = (1/64) * sum_d allparam[l*8192 + 4096 + d*65], wave 0 computes ---
    if (tid < 64) {
        for (int l = 0; l < NLAYER; ++l) {
            float v = allparam[l * 8192 + 4096 + tid * 65];
            #pragma unroll
            for (int off = 32; off > 0; off >>= 1)
                v += __shfl_down(v, off, 64);
            if (tid == 0) qs[l] = v * (1.0f / 64.0f);
        }
    }

    // --- stage tile to LDS; pass-through copy of columns 0..63 (unchanged) ---
    for (int idx = tid; idx < NROW * NCOL; idx += TPB) {
        float v = Zin[base + idx];
        Zs[idx] = v;
        if (idx % NCOL != DD) out[base + idx] = v;   // col 64 written at the end
    }
    for (int n = tid; n < NROW; n += TPB) rS[n] = 0.0f;
    __syncthreads();

    for (int l = 0; l < NLAYER; ++l) {
        // --- s_j = sum_{m<512} y[m] * X[m][j] ---
        {
            const int j = tid & 63;
            const int g = tid >> 6;                  // 0..15
            const int m0 = g * (NN / NGRP);          // 32 rows per group
            float p = 0.0f;
            #pragma unroll 4
            for (int m = m0; m < m0 + NN / NGRP; ++m)
                p += Zs[m * NCOL + DD] * Zs[m * NCOL + j];  // y broadcast + stride-1
            sred[g][j] = p;
        }
        __syncthreads();
        if (tid < 64) {
            float p = 0.0f;
            #pragma unroll
            for (int g = 0; g < NGRP; ++g) p += sred[g][tid];
            sv[tid] = p;
        }
        __syncthreads();

        // --- y[n] update (all 513 rows) ---
        const float c  = qs[l] * (1.0f / (float)NN);
        const float gm = gam[l];
        const float al = alp[l];
        for (int n = tid; n < NROW; n += TPB) {
            float dot = 0.0f;
            #pragma unroll
            for (int j = 0; j < DD; ++j) dot += Zs[n * NCOL + j] * sv[j];
            const float rr = rS[n] * gm + c * dot;
            rS[n] = rr;
            Zs[n * NCOL + DD] += rr * al;
        }
        __syncthreads();
    }

    // --- write final column 64 ---
    for (int n = tid; n < NROW; n += TPB)
        out[base + n * NCOL + DD] = Zs[n * NCOL + DD];
}

extern "C" void kernel_launch(void* const* d_in, const int* in_sizes, int n_in,
                              void* d_out, int out_size, void* d_ws, size_t ws_size,
                              hipStream_t stream) {
    const float* Z        = (const float*)d_in[0];
    const float* allparam = (const float*)d_in[1];
    const float* gam      = (const float*)d_in[2];
    const float* alp      = (const float*)d_in[3];
    float* out = (float*)d_out;
    tf_kernel<<<dim3(512), dim3(TPB), 0, stream>>>(Z, allparam, gam, alp, out);
}